// Round 3
// baseline (872.823 us; speedup 1.0000x reference)
//
#include <hip/hip_runtime.h>
#include <hip/hip_bf16.h>
#include <hip/hip_cooperative_groups.h>

namespace cg = cooperative_groups;

// Problem constants (fixed by the reference).
#define NNODES 10000
#define NEDGES 160000
#define FIN    2208
#define HDIM   512
#define NCLS   2

#define MPAD   10240     // 80 * 128
#define K1PAD  2240      // 2208 padded to multiple of 64
#define BCAP   128       // per-node edge bucket capacity (max degree ~35 here)
#define GRID   640       // persistent cooperative grid (1 GEMM tile per block)

typedef __bf16 bf16x8 __attribute__((ext_vector_type(8)));
typedef float  f32x4  __attribute__((ext_vector_type(4)));
typedef unsigned short u16x8 __attribute__((ext_vector_type(8)));

__device__ inline unsigned short f2bf(float f) {
    union { float f; unsigned int u; } v; v.f = f;
    return (unsigned short)((v.u + 0x7FFFu + ((v.u >> 16) & 1u)) >> 16);
}
__device__ inline float bf2f(unsigned short u) {
    union { unsigned int i; float f; } v; v.i = ((unsigned int)u) << 16; return v.f;
}

// ---------------- bf16 MFMA GEMM body (baseline single-buffer form) ----------
#define BKK 64
#define GG1 640

__device__ __forceinline__ void gemm_body(
    const unsigned short* __restrict__ A, const unsigned short* __restrict__ Bt,
    unsigned short* __restrict__ C, int M, int K, int l) {
    __shared__ char As[128 * BKK * 2] __attribute__((aligned(16)));
    __shared__ char Bs[64 * BKK * 2]  __attribute__((aligned(16)));
    const int tid  = threadIdx.x;
    const int lane = tid & 63;
    const int w    = tid >> 6;
    const int wm   = w & 1, wn = w >> 1;
    const int quad = lane >> 4, lq = lane & 15;

    const int xcd   = l & 7;
    const int q     = l >> 3;
    const int strip = (q >> 3) * 8 + xcd;
    const int bm    = strip * 128;
    const int bn    = (q & 7) * 64;

    f32x4 acc[4][2] = {};

    for (int k0 = 0; k0 < K; k0 += BKK) {
        #pragma unroll
        for (int i = 0; i < 4; ++i) {
            int c = i * 256 + tid;
            int r = c >> 3;
            int g = (c & 7) ^ (r & 7);
            const char* gpA = (const char*)A + ((size_t)(bm + r) * K + k0) * 2 + (g << 4);
            __builtin_amdgcn_global_load_lds(
                (const __attribute__((address_space(1))) void*)gpA,
                (__attribute__((address_space(3))) void*)(As + c * 16), 16, 0, 0);
        }
        #pragma unroll
        for (int i = 0; i < 2; ++i) {
            int c = i * 256 + tid;
            int r = c >> 3;
            int g = (c & 7) ^ (r & 7);
            const char* gpB = (const char*)Bt + ((size_t)(bn + r) * K + k0) * 2 + (g << 4);
            __builtin_amdgcn_global_load_lds(
                (const __attribute__((address_space(1))) void*)gpB,
                (__attribute__((address_space(3))) void*)(Bs + c * 16), 16, 0, 0);
        }
        __syncthreads();

        #pragma unroll
        for (int s = 0; s < 2; ++s) {
            bf16x8 af[4], bfr[2];
            int g = s * 4 + quad;
            #pragma unroll
            for (int i = 0; i < 4; ++i) {
                int r = wm * 64 + i * 16 + lq;
                af[i] = *(const bf16x8*)(As + r * 128 + ((g ^ (r & 7)) << 4));
            }
            #pragma unroll
            for (int j = 0; j < 2; ++j) {
                int n = wn * 32 + j * 16 + lq;
                bfr[j] = *(const bf16x8*)(Bs + n * 128 + ((g ^ (n & 7)) << 4));
            }
            #pragma unroll
            for (int i = 0; i < 4; ++i)
                #pragma unroll
                for (int j = 0; j < 2; ++j)
                    acc[i][j] = __builtin_amdgcn_mfma_f32_16x16x32_bf16(
                        af[i], bfr[j], acc[i][j], 0, 0, 0);
        }
        __syncthreads();
    }

    #pragma unroll
    for (int i = 0; i < 4; ++i) {
        #pragma unroll
        for (int p = 0; p < 4; ++p) {
            int r = bm + wm * 64 + i * 16 + quad * 4 + p;
            if (r < M) {
                #pragma unroll
                for (int j = 0; j < 2; ++j) {
                    int col = bn + wn * 32 + j * 16 + lq;
                    C[(size_t)r * HDIM + col] = f2bf(acc[i][j][p]);
                }
            }
        }
    }
}

// ---------------- agg body (inline dinv from cnt), FUSE4=1 adds W4 GEMV ------
template<int FUSE4>
__device__ __forceinline__ void agg_node(
    const unsigned short* __restrict__ Y, const int* __restrict__ cnt,
    const int* __restrict__ bucket, const float* __restrict__ bias,
    unsigned short* __restrict__ Hb, const float* __restrict__ W4,
    float* __restrict__ Y4, int w, int lane)
{
    if (!FUSE4 && w >= NNODES) {       // zero pad rows so GEMM A-tiles are clean
        u16x8 z = {0, 0, 0, 0, 0, 0, 0, 0};
        *(u16x8*)(Hb + (size_t)w * HDIM + lane * 8) = z;
        return;
    }
    float di = rsqrtf((float)cnt[w] + 1.0f);
    float sw = di * di;
    u16x8 own = *(const u16x8*)(Y + (size_t)w * HDIM + lane * 8);
    float acc[8];
    #pragma unroll
    for (int t = 0; t < 8; ++t) acc[t] = sw * bf2f(own[t]);

    const int* col = bucket + w * BCAP;
    int deg = cnt[w];
    int e = 0;
    for (; e + 8 <= deg; e += 8) {
        int s0 = col[e + 0], s1 = col[e + 1], s2 = col[e + 2], s3 = col[e + 3];
        int s4 = col[e + 4], s5 = col[e + 5], s6 = col[e + 6], s7 = col[e + 7];
        float w0 = di * rsqrtf((float)cnt[s0] + 1.0f);
        float w1 = di * rsqrtf((float)cnt[s1] + 1.0f);
        float w2 = di * rsqrtf((float)cnt[s2] + 1.0f);
        float w3 = di * rsqrtf((float)cnt[s3] + 1.0f);
        float w4 = di * rsqrtf((float)cnt[s4] + 1.0f);
        float w5 = di * rsqrtf((float)cnt[s5] + 1.0f);
        float w6 = di * rsqrtf((float)cnt[s6] + 1.0f);
        float w7 = di * rsqrtf((float)cnt[s7] + 1.0f);
        u16x8 v0 = *(const u16x8*)(Y + (size_t)s0 * HDIM + lane * 8);
        u16x8 v1 = *(const u16x8*)(Y + (size_t)s1 * HDIM + lane * 8);
        u16x8 v2 = *(const u16x8*)(Y + (size_t)s2 * HDIM + lane * 8);
        u16x8 v3 = *(const u16x8*)(Y + (size_t)s3 * HDIM + lane * 8);
        u16x8 v4 = *(const u16x8*)(Y + (size_t)s4 * HDIM + lane * 8);
        u16x8 v5 = *(const u16x8*)(Y + (size_t)s5 * HDIM + lane * 8);
        u16x8 v6 = *(const u16x8*)(Y + (size_t)s6 * HDIM + lane * 8);
        u16x8 v7 = *(const u16x8*)(Y + (size_t)s7 * HDIM + lane * 8);
        #pragma unroll
        for (int t = 0; t < 8; ++t) {
            acc[t] += w0 * bf2f(v0[t]);
            acc[t] += w1 * bf2f(v1[t]);
            acc[t] += w2 * bf2f(v2[t]);
            acc[t] += w3 * bf2f(v3[t]);
            acc[t] += w4 * bf2f(v4[t]);
            acc[t] += w5 * bf2f(v5[t]);
            acc[t] += w6 * bf2f(v6[t]);
            acc[t] += w7 * bf2f(v7[t]);
        }
    }
    for (; e < deg; ++e) {
        int s = col[e];
        float wg = di * rsqrtf((float)cnt[s] + 1.0f);
        u16x8 v = *(const u16x8*)(Y + (size_t)s * HDIM + lane * 8);
        #pragma unroll
        for (int t = 0; t < 8; ++t) acc[t] += wg * bf2f(v[t]);
    }

    float4 b0 = ((const float4*)bias)[lane * 2];
    float4 b1 = ((const float4*)bias)[lane * 2 + 1];
    acc[0] += b0.x; acc[1] += b0.y; acc[2] += b0.z; acc[3] += b0.w;
    acc[4] += b1.x; acc[5] += b1.y; acc[6] += b1.z; acc[7] += b1.w;

    if (!FUSE4) {
        u16x8 o;
        #pragma unroll
        for (int t = 0; t < 8; ++t) o[t] = f2bf(fmaxf(acc[t], 0.0f));
        *(u16x8*)(Hb + (size_t)w * HDIM + lane * 8) = o;
    } else {
        #pragma unroll
        for (int t = 0; t < 8; ++t) acc[t] = fmaxf(acc[t], 0.0f);
        const float4* wf = (const float4*)W4;
        float4 w0 = wf[lane * 4 + 0];
        float4 w1 = wf[lane * 4 + 1];
        float4 w2 = wf[lane * 4 + 2];
        float4 w3 = wf[lane * 4 + 3];
        float z0 = acc[0]*w0.x + acc[1]*w0.z + acc[2]*w1.x + acc[3]*w1.z
                 + acc[4]*w2.x + acc[5]*w2.z + acc[6]*w3.x + acc[7]*w3.z;
        float z1 = acc[0]*w0.y + acc[1]*w0.w + acc[2]*w1.y + acc[3]*w1.w
                 + acc[4]*w2.y + acc[5]*w2.w + acc[6]*w3.y + acc[7]*w3.w;
        #pragma unroll
        for (int off = 32; off > 0; off >>= 1) {
            z0 += __shfl_down(z0, off);
            z1 += __shfl_down(z1, off);
        }
        if (lane == 0) {
            Y4[2 * w] = z0;
            Y4[2 * w + 1] = z1;
        }
    }
}

// ================= fused persistent cooperative kernel =================
// 8 phases, 7 grid syncs. 640 blocks x 256 thr; 24 KB LDS; 3 blocks/CU cap.
__global__ __launch_bounds__(256, 3) void k_fused(
    const float* __restrict__ x, const int* __restrict__ ei,
    const float* __restrict__ W1, const float* __restrict__ b1,
    const float* __restrict__ W2, const float* __restrict__ b2,
    const float* __restrict__ W3, const float* __restrict__ b3,
    const float* __restrict__ W4, const float* __restrict__ b4,
    float* __restrict__ out,
    int* __restrict__ cnt, int* __restrict__ bucket, float* __restrict__ Y4,
    unsigned short* __restrict__ xb, unsigned short* __restrict__ W1t,
    unsigned short* __restrict__ W2t, unsigned short* __restrict__ W3t,
    unsigned short* __restrict__ Yb, unsigned short* __restrict__ Hb)
{
    cg::grid_group grid = cg::this_grid();
    const int tid  = threadIdx.x;
    const int bid  = blockIdx.x;
    const int lane = tid & 63;
    const int gwave = bid * 4 + (tid >> 6);    // 0..2559

    // ---- Phase A: weight transposes + cnt zero + x->bf16 convert ----
    for (int u = bid; u < 14 * HDIM; u += GRID) {
        int bx = u % 14;
        int n  = u / 14;
        if (bx < 9) {
            int k = bx * 256 + tid;
            if (k < K1PAD) {
                float v = (k < FIN) ? W1[(size_t)k * HDIM + n] : 0.0f;
                W1t[(size_t)n * K1PAD + k] = f2bf(v);
            }
        } else if (bx < 11) {
            int k = (bx - 9) * 256 + tid;
            W2t[(size_t)n * HDIM + k] = f2bf(W2[(size_t)k * HDIM + n]);
        } else if (bx < 13) {
            int k = (bx - 11) * 256 + tid;
            W3t[(size_t)n * HDIM + k] = f2bf(W3[(size_t)k * HDIM + n]);
        } else {
            int i = n * 256 + tid;
            if (i < NNODES) cnt[i] = 0;
        }
    }
    for (int row = bid; row < MPAD; row += GRID) {
        unsigned short* orow = xb + (size_t)row * K1PAD;
        u16x8 z = {0, 0, 0, 0, 0, 0, 0, 0};
        if (row >= NNODES) {
            for (int c = tid; c < K1PAD / 8; c += 256) *(u16x8*)(orow + c * 8) = z;
        } else {
            const float* irow = x + (size_t)row * FIN;
            for (int c = tid; c < K1PAD / 8; c += 256) {
                int col = c * 8;
                u16x8 o = z;
                if (col + 8 <= FIN) {
                    float4 f0 = *(const float4*)(irow + col);
                    float4 f1 = *(const float4*)(irow + col + 4);
                    o[0] = f2bf(f0.x); o[1] = f2bf(f0.y); o[2] = f2bf(f0.z); o[3] = f2bf(f0.w);
                    o[4] = f2bf(f1.x); o[5] = f2bf(f1.y); o[6] = f2bf(f1.z); o[7] = f2bf(f1.w);
                }
                *(u16x8*)(orow + col) = o;
            }
        }
    }
    grid.sync();

    // ---- Phase B: edge fill (cnt atomics) + GEMM1 ----
    for (int i = bid * 256 + tid; i < NEDGES; i += GRID * 256) {
        int src = ei[i];
        int dst = ei[NEDGES + i];
        int pos = atomicAdd(&cnt[dst], 1);
        bucket[dst * BCAP + pos] = src;
    }
    gemm_body(xb, W1t, Yb, NNODES, K1PAD, bid);
    grid.sync();

    // ---- Phase C: agg layer 1 (dinv inline from cnt) ----
    for (int w = gwave; w < MPAD; w += 2560)
        agg_node<0>(Yb, cnt, bucket, b1, Hb, nullptr, nullptr, w, lane);
    grid.sync();

    // ---- Phase D: GEMM2 ----
    gemm_body(Hb, W2t, Yb, NNODES, HDIM, bid);
    grid.sync();

    // ---- Phase E: agg layer 2 ----
    for (int w = gwave; w < MPAD; w += 2560)
        agg_node<0>(Yb, cnt, bucket, b2, Hb, nullptr, nullptr, w, lane);
    grid.sync();

    // ---- Phase F: GEMM3 ----
    gemm_body(Hb, W3t, Yb, NNODES, HDIM, bid);
    grid.sync();

    // ---- Phase G: agg layer 3 + fused W4 GEMV -> Y4 ----
    for (int w = gwave; w < NNODES; w += 2560)
        agg_node<1>(Yb, cnt, bucket, b3, nullptr, W4, Y4, w, lane);
    grid.sync();

    // ---- Phase H: layer-4 aggregation + bias + log_softmax ----
    for (int i = bid * 256 + tid; i < NNODES; i += GRID * 256) {
        float di = rsqrtf((float)cnt[i] + 1.0f);
        float sw = di * di;
        float z0 = sw * Y4[2 * i];
        float z1 = sw * Y4[2 * i + 1];
        const int* col = bucket + i * BCAP;
        int deg = cnt[i];
        for (int e = 0; e < deg; ++e) {
            int s = col[e];
            float wgt = di * rsqrtf((float)cnt[s] + 1.0f);
            z0 += wgt * Y4[2 * s];
            z1 += wgt * Y4[2 * s + 1];
        }
        z0 += b4[0];
        z1 += b4[1];
        float m = fmaxf(z0, z1);
        float l = m + logf(expf(z0 - m) + expf(z1 - m));
        out[2 * i] = z0 - l;
        out[2 * i + 1] = z1 - l;
    }
}

// ================= fallback: verified 9-dispatch baseline =================

__global__ void k_prep(const float* __restrict__ W1, const float* __restrict__ W2,
                       const float* __restrict__ W3, unsigned short* __restrict__ W1t,
                       unsigned short* __restrict__ W2t, unsigned short* __restrict__ W3t,
                       int* __restrict__ cnt) {
    int n = blockIdx.y;
    int bx = blockIdx.x;
    int t = threadIdx.x;
    if (bx < 9) {
        int k = bx * 256 + t;
        if (k < K1PAD) {
            float v = (k < FIN) ? W1[(size_t)k * HDIM + n] : 0.0f;
            W1t[(size_t)n * K1PAD + k] = f2bf(v);
        }
    } else if (bx < 11) {
        int k = (bx - 9) * 256 + t;
        W2t[(size_t)n * HDIM + k] = f2bf(W2[(size_t)k * HDIM + n]);
    } else if (bx < 13) {
        int k = (bx - 11) * 256 + t;
        W3t[(size_t)n * HDIM + k] = f2bf(W3[(size_t)k * HDIM + n]);
    } else {
        int i = n * 256 + t;
        if (i < NNODES) cnt[i] = 0;
    }
}

__global__ void k_cvt_fill(const float* __restrict__ x, unsigned short* __restrict__ xb,
                           const int* __restrict__ ei, int* __restrict__ cnt,
                           int* __restrict__ bucket) {
    int bx = blockIdx.x;
    int t = threadIdx.x;
    if (bx >= MPAD) {
        int i = (bx - MPAD) * 256 + t;
        if (i < NEDGES) {
            int src = ei[i];
            int dst = ei[NEDGES + i];
            int pos = atomicAdd(&cnt[dst], 1);
            bucket[dst * BCAP + pos] = src;
        }
        return;
    }
    int row = bx;
    unsigned short* orow = xb + (size_t)row * K1PAD;
    u16x8 z = {0, 0, 0, 0, 0, 0, 0, 0};
    if (row >= NNODES) {
        for (int c = t; c < K1PAD / 8; c += 256) *(u16x8*)(orow + c * 8) = z;
        return;
    }
    const float* irow = x + (size_t)row * FIN;
    for (int c = t; c < K1PAD / 8; c += 256) {
        int col = c * 8;
        u16x8 o = z;
        if (col + 8 <= FIN) {
            float4 f0 = *(const float4*)(irow + col);
            float4 f1 = *(const float4*)(irow + col + 4);
            o[0] = f2bf(f0.x); o[1] = f2bf(f0.y); o[2] = f2bf(f0.z); o[3] = f2bf(f0.w);
            o[4] = f2bf(f1.x); o[5] = f2bf(f1.y); o[6] = f2bf(f1.z); o[7] = f2bf(f1.w);
        }
        *(u16x8*)(orow + col) = o;
    }
}

__global__ __launch_bounds__(256) void k_gemm1_dinv(
    const unsigned short* __restrict__ A, const unsigned short* __restrict__ Bt,
    unsigned short* __restrict__ C, int M, int K,
    const int* __restrict__ cnt, float* __restrict__ dinv) {
    int bx = blockIdx.x;
    if (bx < GG1) { gemm_body(A, Bt, C, M, K, bx); return; }
    int i = (bx - GG1) * 256 + threadIdx.x;
    if (i < NNODES) dinv[i] = rsqrtf((float)cnt[i] + 1.0f);
}

__global__ __launch_bounds__(256) void k_gemm_bf16(
    const unsigned short* __restrict__ A, const unsigned short* __restrict__ Bt,
    unsigned short* __restrict__ C, int M, int K) {
    gemm_body(A, Bt, C, M, K, blockIdx.x);
}

__global__ void k_agg(const unsigned short* __restrict__ Y, const float* __restrict__ dinv,
                      const int* __restrict__ cnt, const int* __restrict__ bucket,
                      const float* __restrict__ bias, unsigned short* __restrict__ Hb) {
    int w = (blockIdx.x * blockDim.x + threadIdx.x) >> 6;
    int lane = threadIdx.x & 63;
    if (w >= MPAD) return;
    unsigned short* hr = Hb + (size_t)w * HDIM + lane * 8;
    if (w >= NNODES) {
        u16x8 z = {0, 0, 0, 0, 0, 0, 0, 0};
        *(u16x8*)hr = z;
        return;
    }
    float di = dinv[w];
    float sw = di * di;
    u16x8 own = *(const u16x8*)(Y + (size_t)w * HDIM + lane * 8);
    float acc[8];
    #pragma unroll
    for (int t = 0; t < 8; ++t) acc[t] = sw * bf2f(own[t]);

    const int* col = bucket + w * BCAP;
    int deg = cnt[w];
    int e = 0;
    for (; e + 4 <= deg; e += 4) {
        int s0 = col[e + 0], s1 = col[e + 1];
        int s2 = col[e + 2], s3 = col[e + 3];
        float w0 = di * dinv[s0], w1 = di * dinv[s1];
        float w2 = di * dinv[s2], w3 = di * dinv[s3];
        u16x8 v0 = *(const u16x8*)(Y + (size_t)s0 * HDIM + lane * 8);
        u16x8 v1 = *(const u16x8*)(Y + (size_t)s1 * HDIM + lane * 8);
        u16x8 v2 = *(const u16x8*)(Y + (size_t)s2 * HDIM + lane * 8);
        u16x8 v3 = *(const u16x8*)(Y + (size_t)s3 * HDIM + lane * 8);
        #pragma unroll
        for (int t = 0; t < 8; ++t) {
            acc[t] += w0 * bf2f(v0[t]);
            acc[t] += w1 * bf2f(v1[t]);
            acc[t] += w2 * bf2f(v2[t]);
            acc[t] += w3 * bf2f(v3[t]);
        }
    }
    for (; e < deg; ++e) {
        int s = col[e];
        float wg = di * dinv[s];
        u16x8 v = *(const u16x8*)(Y + (size_t)s * HDIM + lane * 8);
        #pragma unroll
        for (int t = 0; t < 8; ++t) acc[t] += wg * bf2f(v[t]);
    }

    float4 b0 = ((const float4*)bias)[lane * 2];
    float4 b1 = ((const float4*)bias)[lane * 2 + 1];
    acc[0] += b0.x; acc[1] += b0.y; acc[2] += b0.z; acc[3] += b0.w;
    acc[4] += b1.x; acc[5] += b1.y; acc[6] += b1.z; acc[7] += b1.w;
    u16x8 o;
    #pragma unroll
    for (int t = 0; t < 8; ++t) o[t] = f2bf(fmaxf(acc[t], 0.0f));
    *(u16x8*)hr = o;
}

__global__ void k_agg_g4(const unsigned short* __restrict__ Y, const float* __restrict__ dinv,
                         const int* __restrict__ cnt, const int* __restrict__ bucket,
                         const float* __restrict__ b3, const float* __restrict__ W4,
                         float* __restrict__ Y4) {
    int w = (blockIdx.x * blockDim.x + threadIdx.x) >> 6;
    int lane = threadIdx.x & 63;
    if (w >= NNODES) return;
    float di = dinv[w];
    float sw = di * di;
    u16x8 own = *(const u16x8*)(Y + (size_t)w * HDIM + lane * 8);
    float acc[8];
    #pragma unroll
    for (int t = 0; t < 8; ++t) acc[t] = sw * bf2f(own[t]);

    const int* col = bucket + w * BCAP;
    int deg = cnt[w];
    int e = 0;
    for (; e + 4 <= deg; e += 4) {
        int s0 = col[e + 0], s1 = col[e + 1];
        int s2 = col[e + 2], s3 = col[e + 3];
        float w0 = di * dinv[s0], w1 = di * dinv[s1];
        float w2 = di * dinv[s2], w3 = di * dinv[s3];
        u16x8 v0 = *(const u16x8*)(Y + (size_t)s0 * HDIM + lane * 8);
        u16x8 v1 = *(const u16x8*)(Y + (size_t)s1 * HDIM + lane * 8);
        u16x8 v2 = *(const u16x8*)(Y + (size_t)s2 * HDIM + lane * 8);
        u16x8 v3 = *(const u16x8*)(Y + (size_t)s3 * HDIM + lane * 8);
        #pragma unroll
        for (int t = 0; t < 8; ++t) {
            acc[t] += w0 * bf2f(v0[t]);
            acc[t] += w1 * bf2f(v1[t]);
            acc[t] += w2 * bf2f(v2[t]);
            acc[t] += w3 * bf2f(v3[t]);
        }
    }
    for (; e < deg; ++e) {
        int s = col[e];
        float wg = di * dinv[s];
        u16x8 v = *(const u16x8*)(Y + (size_t)s * HDIM + lane * 8);
        #pragma unroll
        for (int t = 0; t < 8; ++t) acc[t] += wg * bf2f(v[t]);
    }

    float4 b0 = ((const float4*)b3)[lane * 2];
    float4 b1 = ((const float4*)b3)[lane * 2 + 1];
    acc[0] += b0.x; acc[1] += b0.y; acc[2] += b0.z; acc[3] += b0.w;
    acc[4] += b1.x; acc[5] += b1.y; acc[6] += b1.z; acc[7] += b1.w;
    #pragma unroll
    for (int t = 0; t < 8; ++t) acc[t] = fmaxf(acc[t], 0.0f);

    const float4* wf = (const float4*)W4;
    float4 w0 = wf[lane * 4 + 0];
    float4 w1 = wf[lane * 4 + 1];
    float4 w2 = wf[lane * 4 + 2];
    float4 w3 = wf[lane * 4 + 3];
    float z0 = acc[0]*w0.x + acc[1]*w0.z + acc[2]*w1.x + acc[3]*w1.z
             + acc[4]*w2.x + acc[5]*w2.z + acc[6]*w3.x + acc[7]*w3.z;
    float z1 = acc[0]*w0.y + acc[1]*w0.w + acc[2]*w1.y + acc[3]*w1.w
             + acc[4]*w2.y + acc[5]*w2.w + acc[6]*w3.y + acc[7]*w3.w;
    #pragma unroll
    for (int off = 32; off > 0; off >>= 1) {
        z0 += __shfl_down(z0, off);
        z1 += __shfl_down(z1, off);
    }
    if (lane == 0) {
        Y4[2 * w] = z0;
        Y4[2 * w + 1] = z1;
    }
}

__global__ void k_final(const float* __restrict__ Y4, const float* __restrict__ dinv,
                        const int* __restrict__ cnt, const int* __restrict__ bucket,
                        const float* __restrict__ b4, float* __restrict__ out, int n) {
    int i = blockIdx.x * blockDim.x + threadIdx.x;
    if (i >= n) return;
    float di = dinv[i];
    float sw = di * di;
    float z0 = sw * Y4[2 * i];
    float z1 = sw * Y4[2 * i + 1];
    const int* col = bucket + i * BCAP;
    int deg = cnt[i];
    for (int e = 0; e < deg; ++e) {
        int s = col[e];
        float wgt = di * dinv[s];
        z0 += wgt * Y4[2 * s];
        z1 += wgt * Y4[2 * s + 1];
    }
    z0 += b4[0];
    z1 += b4[1];
    float m = fmaxf(z0, z1);
    float l = m + logf(expf(z0 - m) + expf(z1 - m));
    out[2 * i] = z0 - l;
    out[2 * i + 1] = z1 - l;
}

// ---------------- launch ----------------

extern "C" void kernel_launch(void* const* d_in, const int* in_sizes, int n_in,
                              void* d_out, int out_size, void* d_ws, size_t ws_size,
                              hipStream_t stream) {
    const float* x  = (const float*)d_in[0];
    const int*   ei = (const int*)d_in[1];
    const float* W1 = (const float*)d_in[3];
    const float* b1 = (const float*)d_in[4];
    const float* W2 = (const float*)d_in[5];
    const float* b2 = (const float*)d_in[6];
    const float* W3 = (const float*)d_in[7];
    const float* b3 = (const float*)d_in[8];
    const float* W4 = (const float*)d_in[9];
    const float* b4 = (const float*)d_in[10];
    float* out = (float*)d_out;

    char* ws = (char*)d_ws;
    // workspace layout (bytes, 256-aligned)
    float*          dinv    = (float*)(ws + 0);                  // 40,960
    int*            cnt     = (int*)  (ws + 40960);              // 40,960
    int*            bucket  = (int*)  (ws + 81920);              // NNODES*BCAP*4 = 5,120,000
    float*          Y4      = (float*)(ws + 5201920);            // 81,920
    unsigned short* xb      = (unsigned short*)(ws + 5283840);   // 45,875,200
    unsigned short* W1t     = (unsigned short*)(ws + 51159040);  // 2,293,760
    unsigned short* W2t     = (unsigned short*)(ws + 53452800);  // 524,288
    unsigned short* W3t     = (unsigned short*)(ws + 53977088);  // 524,288
    unsigned short* Yb      = (unsigned short*)(ws + 54501376);  // 10,485,760
    unsigned short* Hb      = (unsigned short*)(ws + 64987136);  // 10,485,760
    // total: 75,472,896
    if (ws_size < 75472896) return;

    // ---- preferred path: single persistent cooperative kernel ----
    void* args[] = { (void*)&x, (void*)&ei,
                     (void*)&W1, (void*)&b1, (void*)&W2, (void*)&b2,
                     (void*)&W3, (void*)&b3, (void*)&W4, (void*)&b4,
                     (void*)&out,
                     (void*)&cnt, (void*)&bucket, (void*)&Y4,
                     (void*)&xb, (void*)&W1t, (void*)&W2t, (void*)&W3t,
                     (void*)&Yb, (void*)&Hb };
    hipError_t err = hipLaunchCooperativeKernel((const void*)k_fused,
        dim3(GRID), dim3(256), args, 0, stream);
    if (err == hipSuccess) return;
    (void)hipGetLastError();   // clear sticky error, fall back

    // ---- fallback: verified 9-dispatch baseline ----
    const int agrid = (MPAD * 64) / 256;
    k_prep<<<dim3(14, HDIM), 256, 0, stream>>>(W1, W2, W3, W1t, W2t, W3t, cnt);
    k_cvt_fill<<<MPAD + 625, 256, 0, stream>>>(x, xb, ei, cnt, bucket);
    k_gemm1_dinv<<<GG1 + 40, 256, 0, stream>>>(xb, W1t, Yb, NNODES, K1PAD, cnt, dinv);
    k_agg<<<agrid, 256, 0, stream>>>(Yb, dinv, cnt, bucket, b1, Hb);
    k_gemm_bf16<<<GG1, 256, 0, stream>>>(Hb, W2t, Yb, NNODES, HDIM);
    k_agg<<<agrid, 256, 0, stream>>>(Yb, dinv, cnt, bucket, b2, Hb);
    k_gemm_bf16<<<GG1, 256, 0, stream>>>(Hb, W3t, Yb, NNODES, HDIM);
    k_agg_g4<<<(NNODES * 64) / 256, 256, 0, stream>>>(Yb, dinv, cnt, bucket, b3, W4, Y4);
    k_final<<<40, 256, 0, stream>>>(Y4, dinv, cnt, bucket, b4, out, NNODES);
}

// Round 4
// 420.581 us; speedup vs baseline: 2.0753x; 2.0753x over previous
//
#include <hip/hip_runtime.h>
#include <hip/hip_bf16.h>

// Problem constants (fixed by the reference).
#define NNODES 10000
#define NEDGES 160000
#define FIN    2208
#define HDIM   512
#define NCLS   2

#define MPAD   10240     // 80 * 128
#define K1PAD  2240      // 2208 padded to multiple of 64
#define BCAP   128       // per-node edge bucket capacity (max degree ~35 here)

typedef __bf16 bf16x8 __attribute__((ext_vector_type(8)));
typedef float  f32x4  __attribute__((ext_vector_type(4)));
typedef unsigned short u16x8 __attribute__((ext_vector_type(8)));

__device__ inline unsigned short f2bf(float f) {
    union { float f; unsigned int u; } v; v.f = f;
    return (unsigned short)((v.u + 0x7FFFu + ((v.u >> 16) & 1u)) >> 16);
}
__device__ inline float bf2f(unsigned short u) {
    union { unsigned int i; float f; } v; v.i = ((unsigned int)u) << 16; return v.f;
}

// ---------------- dispatch 1: weight transposes + cnt zero ----------------
__global__ void k_prep(const float* __restrict__ W1, const float* __restrict__ W2,
                       const float* __restrict__ W3, unsigned short* __restrict__ W1t,
                       unsigned short* __restrict__ W2t, unsigned short* __restrict__ W3t,
                       int* __restrict__ cnt) {
    int n = blockIdx.y;
    int bx = blockIdx.x;
    int t = threadIdx.x;
    if (bx < 9) {
        int k = bx * 256 + t;
        if (k < K1PAD) {
            float v = (k < FIN) ? W1[(size_t)k * HDIM + n] : 0.0f;
            W1t[(size_t)n * K1PAD + k] = f2bf(v);
        }
    } else if (bx < 11) {
        int k = (bx - 9) * 256 + t;
        W2t[(size_t)n * HDIM + k] = f2bf(W2[(size_t)k * HDIM + n]);
    } else if (bx < 13) {
        int k = (bx - 11) * 256 + t;
        W3t[(size_t)n * HDIM + k] = f2bf(W3[(size_t)k * HDIM + n]);
    } else {
        int i = n * 256 + t;
        if (i < NNODES) cnt[i] = 0;
    }
}

// ---------------- dispatch 2: x->bf16 convert + bucketed hist/fill -----------
__global__ void k_cvt_fill(const float* __restrict__ x, unsigned short* __restrict__ xb,
                           const int* __restrict__ ei, int* __restrict__ cnt,
                           int* __restrict__ bucket) {
    int bx = blockIdx.x;
    int t = threadIdx.x;
    if (bx >= MPAD) {                      // hist+fill part
        int i = (bx - MPAD) * 256 + t;
        if (i < NEDGES) {
            int src = ei[i];
            int dst = ei[NEDGES + i];
            int pos = atomicAdd(&cnt[dst], 1);
            bucket[dst * BCAP + pos] = src;
        }
        return;
    }
    int row = bx;                          // convert part
    unsigned short* orow = xb + (size_t)row * K1PAD;
    u16x8 z = {0, 0, 0, 0, 0, 0, 0, 0};
    if (row >= NNODES) {
        for (int c = t; c < K1PAD / 8; c += 256) *(u16x8*)(orow + c * 8) = z;
        return;
    }
    const float* irow = x + (size_t)row * FIN;
    for (int c = t; c < K1PAD / 8; c += 256) {
        int col = c * 8;
        u16x8 o = z;
        if (col + 8 <= FIN) {
            float4 f0 = *(const float4*)(irow + col);
            float4 f1 = *(const float4*)(irow + col + 4);
            o[0] = f2bf(f0.x); o[1] = f2bf(f0.y); o[2] = f2bf(f0.z); o[3] = f2bf(f0.w);
            o[4] = f2bf(f1.x); o[5] = f2bf(f1.y); o[6] = f2bf(f1.z); o[7] = f2bf(f1.w);
        }
        *(u16x8*)(orow + col) = o;
    }
}

// ---------------- bf16 MFMA GEMM body (baseline single-buffer form) ----------
#define BKK 64
#define GG1 640

__device__ __forceinline__ void gemm_body(
    const unsigned short* __restrict__ A, const unsigned short* __restrict__ Bt,
    unsigned short* __restrict__ C, int M, int K, int l) {
    __shared__ char As[128 * BKK * 2] __attribute__((aligned(16)));
    __shared__ char Bs[64 * BKK * 2]  __attribute__((aligned(16)));
    const int tid  = threadIdx.x;
    const int lane = tid & 63;
    const int w    = tid >> 6;
    const int wm   = w & 1, wn = w >> 1;
    const int quad = lane >> 4, lq = lane & 15;

    const int xcd   = l & 7;
    const int q     = l >> 3;
    const int strip = (q >> 3) * 8 + xcd;
    const int bm    = strip * 128;
    const int bn    = (q & 7) * 64;

    f32x4 acc[4][2] = {};

    for (int k0 = 0; k0 < K; k0 += BKK) {
        #pragma unroll
        for (int i = 0; i < 4; ++i) {
            int c = i * 256 + tid;
            int r = c >> 3;
            int g = (c & 7) ^ (r & 7);
            const char* gpA = (const char*)A + ((size_t)(bm + r) * K + k0) * 2 + (g << 4);
            __builtin_amdgcn_global_load_lds(
                (const __attribute__((address_space(1))) void*)gpA,
                (__attribute__((address_space(3))) void*)(As + c * 16), 16, 0, 0);
        }
        #pragma unroll
        for (int i = 0; i < 2; ++i) {
            int c = i * 256 + tid;
            int r = c >> 3;
            int g = (c & 7) ^ (r & 7);
            const char* gpB = (const char*)Bt + ((size_t)(bn + r) * K + k0) * 2 + (g << 4);
            __builtin_amdgcn_global_load_lds(
                (const __attribute__((address_space(1))) void*)gpB,
                (__attribute__((address_space(3))) void*)(Bs + c * 16), 16, 0, 0);
        }
        __syncthreads();

        #pragma unroll
        for (int s = 0; s < 2; ++s) {
            bf16x8 af[4], bfr[2];
            int g = s * 4 + quad;
            #pragma unroll
            for (int i = 0; i < 4; ++i) {
                int r = wm * 64 + i * 16 + lq;
                af[i] = *(const bf16x8*)(As + r * 128 + ((g ^ (r & 7)) << 4));
            }
            #pragma unroll
            for (int j = 0; j < 2; ++j) {
                int n = wn * 32 + j * 16 + lq;
                bfr[j] = *(const bf16x8*)(Bs + n * 128 + ((g ^ (n & 7)) << 4));
            }
            #pragma unroll
            for (int i = 0; i < 4; ++i)
                #pragma unroll
                for (int j = 0; j < 2; ++j)
                    acc[i][j] = __builtin_amdgcn_mfma_f32_16x16x32_bf16(
                        af[i], bfr[j], acc[i][j], 0, 0, 0);
        }
        __syncthreads();
    }

    #pragma unroll
    for (int i = 0; i < 4; ++i) {
        #pragma unroll
        for (int p = 0; p < 4; ++p) {
            int r = bm + wm * 64 + i * 16 + quad * 4 + p;
            if (r < M) {
                #pragma unroll
                for (int j = 0; j < 2; ++j) {
                    int col = bn + wn * 32 + j * 16 + lq;
                    C[(size_t)r * HDIM + col] = f2bf(acc[i][j][p]);
                }
            }
        }
    }
}

// ---------------- dispatch 3: GEMM1 (640 blocks, REPS for telemetry) ---------
// TELEMETRY: reps>1 re-executes the identical tile (idempotent: same C values
// rewritten). Opaque lv defeats CSE so each rep does full staging + MFMA.
__global__ __launch_bounds__(256) void k_gemm1_dinv(
    const unsigned short* __restrict__ A, const unsigned short* __restrict__ Bt,
    unsigned short* __restrict__ C, int M, int K,
    const int* __restrict__ cnt, float* __restrict__ dinv, int reps) {
    int bx = blockIdx.x;
    if (bx < GG1) {
        for (int rep = 0; rep < reps; ++rep) {
            int lv = bx;
            asm volatile("" : "+v"(lv));
            gemm_body(A, Bt, C, M, K, lv);
        }
        return;
    }
    int i = (bx - GG1) * 256 + threadIdx.x;
    if (i < NNODES) dinv[i] = rsqrtf((float)cnt[i] + 1.0f);
}

// ---------------- GEMM (layers 2/3) ----------------
__global__ __launch_bounds__(256) void k_gemm_bf16(
    const unsigned short* __restrict__ A, const unsigned short* __restrict__ Bt,
    unsigned short* __restrict__ C, int M, int K) {
    gemm_body(A, Bt, C, M, K, blockIdx.x);
}

// ---------------- aggregation (layers 1/2): 1 wave per node ----------------
// TELEMETRY: reps>1 re-runs the full per-node body (idempotent; opaque wv
// forces full re-gather). d4 launches reps=4 so this dispatch exceeds the
// 51-us harness fills and surfaces in the top-5 with real counters.
__global__ void k_agg(const unsigned short* __restrict__ Y, const float* __restrict__ dinv,
                      const int* __restrict__ cnt, const int* __restrict__ bucket,
                      const float* __restrict__ bias, unsigned short* __restrict__ Hb,
                      int reps) {
    int w0_ = (blockIdx.x * blockDim.x + threadIdx.x) >> 6;
    int lane = threadIdx.x & 63;
    if (w0_ >= MPAD) return;

    for (int rep = 0; rep < reps; ++rep) {
        int w = w0_;
        asm volatile("" : "+v"(w));
        unsigned short* hr = Hb + (size_t)w * HDIM + lane * 8;
        if (w >= NNODES) {
            u16x8 z = {0, 0, 0, 0, 0, 0, 0, 0};
            *(u16x8*)hr = z;
            continue;
        }
        float di = dinv[w];
        float sw = di * di;
        u16x8 own = *(const u16x8*)(Y + (size_t)w * HDIM + lane * 8);
        float acc[8];
        #pragma unroll
        for (int t = 0; t < 8; ++t) acc[t] = sw * bf2f(own[t]);

        const int* col = bucket + w * BCAP;
        int deg = cnt[w];
        int e = 0;
        for (; e + 4 <= deg; e += 4) {
            int s0 = col[e + 0], s1 = col[e + 1];
            int s2 = col[e + 2], s3 = col[e + 3];
            float w0 = di * dinv[s0], w1 = di * dinv[s1];
            float w2 = di * dinv[s2], w3 = di * dinv[s3];
            u16x8 v0 = *(const u16x8*)(Y + (size_t)s0 * HDIM + lane * 8);
            u16x8 v1 = *(const u16x8*)(Y + (size_t)s1 * HDIM + lane * 8);
            u16x8 v2 = *(const u16x8*)(Y + (size_t)s2 * HDIM + lane * 8);
            u16x8 v3 = *(const u16x8*)(Y + (size_t)s3 * HDIM + lane * 8);
            #pragma unroll
            for (int t = 0; t < 8; ++t) {
                acc[t] += w0 * bf2f(v0[t]);
                acc[t] += w1 * bf2f(v1[t]);
                acc[t] += w2 * bf2f(v2[t]);
                acc[t] += w3 * bf2f(v3[t]);
            }
        }
        for (; e < deg; ++e) {
            int s = col[e];
            float wg = di * dinv[s];
            u16x8 v = *(const u16x8*)(Y + (size_t)s * HDIM + lane * 8);
            #pragma unroll
            for (int t = 0; t < 8; ++t) acc[t] += wg * bf2f(v[t]);
        }

        float4 b0 = ((const float4*)bias)[lane * 2];
        float4 b1 = ((const float4*)bias)[lane * 2 + 1];
        acc[0] += b0.x; acc[1] += b0.y; acc[2] += b0.z; acc[3] += b0.w;
        acc[4] += b1.x; acc[5] += b1.y; acc[6] += b1.z; acc[7] += b1.w;
        u16x8 o;
        #pragma unroll
        for (int t = 0; t < 8; ++t) o[t] = f2bf(fmaxf(acc[t], 0.0f));
        *(u16x8*)hr = o;
    }
}

// ---------------- agg3 + relu + layer-4 GEMM fused ----------------
__global__ void k_agg_g4(const unsigned short* __restrict__ Y, const float* __restrict__ dinv,
                         const int* __restrict__ cnt, const int* __restrict__ bucket,
                         const float* __restrict__ b3, const float* __restrict__ W4,
                         float* __restrict__ Y4) {
    int w = (blockIdx.x * blockDim.x + threadIdx.x) >> 6;
    int lane = threadIdx.x & 63;
    if (w >= NNODES) return;
    float di = dinv[w];
    float sw = di * di;
    u16x8 own = *(const u16x8*)(Y + (size_t)w * HDIM + lane * 8);
    float acc[8];
    #pragma unroll
    for (int t = 0; t < 8; ++t) acc[t] = sw * bf2f(own[t]);

    const int* col = bucket + w * BCAP;
    int deg = cnt[w];
    int e = 0;
    for (; e + 4 <= deg; e += 4) {
        int s0 = col[e + 0], s1 = col[e + 1];
        int s2 = col[e + 2], s3 = col[e + 3];
        float w0 = di * dinv[s0], w1 = di * dinv[s1];
        float w2 = di * dinv[s2], w3 = di * dinv[s3];
        u16x8 v0 = *(const u16x8*)(Y + (size_t)s0 * HDIM + lane * 8);
        u16x8 v1 = *(const u16x8*)(Y + (size_t)s1 * HDIM + lane * 8);
        u16x8 v2 = *(const u16x8*)(Y + (size_t)s2 * HDIM + lane * 8);
        u16x8 v3 = *(const u16x8*)(Y + (size_t)s3 * HDIM + lane * 8);
        #pragma unroll
        for (int t = 0; t < 8; ++t) {
            acc[t] += w0 * bf2f(v0[t]);
            acc[t] += w1 * bf2f(v1[t]);
            acc[t] += w2 * bf2f(v2[t]);
            acc[t] += w3 * bf2f(v3[t]);
        }
    }
    for (; e < deg; ++e) {
        int s = col[e];
        float wg = di * dinv[s];
        u16x8 v = *(const u16x8*)(Y + (size_t)s * HDIM + lane * 8);
        #pragma unroll
        for (int t = 0; t < 8; ++t) acc[t] += wg * bf2f(v[t]);
    }

    float4 b0 = ((const float4*)b3)[lane * 2];
    float4 b1 = ((const float4*)b3)[lane * 2 + 1];
    acc[0] += b0.x; acc[1] += b0.y; acc[2] += b0.z; acc[3] += b0.w;
    acc[4] += b1.x; acc[5] += b1.y; acc[6] += b1.z; acc[7] += b1.w;
    #pragma unroll
    for (int t = 0; t < 8; ++t) acc[t] = fmaxf(acc[t], 0.0f);

    const float4* wf = (const float4*)W4;
    float4 w0 = wf[lane * 4 + 0];
    float4 w1 = wf[lane * 4 + 1];
    float4 w2 = wf[lane * 4 + 2];
    float4 w3 = wf[lane * 4 + 3];
    float z0 = acc[0]*w0.x + acc[1]*w0.z + acc[2]*w1.x + acc[3]*w1.z
             + acc[4]*w2.x + acc[5]*w2.z + acc[6]*w3.x + acc[7]*w3.z;
    float z1 = acc[0]*w0.y + acc[1]*w0.w + acc[2]*w1.y + acc[3]*w1.w
             + acc[4]*w2.y + acc[5]*w2.w + acc[6]*w3.y + acc[7]*w3.w;
    #pragma unroll
    for (int off = 32; off > 0; off >>= 1) {
        z0 += __shfl_down(z0, off);
        z1 += __shfl_down(z1, off);
    }
    if (lane == 0) {
        Y4[2 * w] = z0;
        Y4[2 * w + 1] = z1;
    }
}

// ---------------- layer-4 aggregation + bias + log_softmax ----------------
__global__ void k_final(const float* __restrict__ Y4, const float* __restrict__ dinv,
                        const int* __restrict__ cnt, const int* __restrict__ bucket,
                        const float* __restrict__ b4, float* __restrict__ out, int n) {
    int i = blockIdx.x * blockDim.x + threadIdx.x;
    if (i >= n) return;
    float di = dinv[i];
    float sw = di * di;
    float z0 = sw * Y4[2 * i];
    float z1 = sw * Y4[2 * i + 1];
    const int* col = bucket + i * BCAP;
    int deg = cnt[i];
    for (int e = 0; e < deg; ++e) {
        int s = col[e];
        float wgt = di * dinv[s];
        z0 += wgt * Y4[2 * s];
        z1 += wgt * Y4[2 * s + 1];
    }
    z0 += b4[0];
    z1 += b4[1];
    float m = fmaxf(z0, z1);
    float l = m + logf(expf(z0 - m) + expf(z1 - m));
    out[2 * i] = z0 - l;
    out[2 * i + 1] = z1 - l;
}

// ---------------- launch ----------------

extern "C" void kernel_launch(void* const* d_in, const int* in_sizes, int n_in,
                              void* d_out, int out_size, void* d_ws, size_t ws_size,
                              hipStream_t stream) {
    const float* x  = (const float*)d_in[0];
    const int*   ei = (const int*)d_in[1];
    const float* W1 = (const float*)d_in[3];
    const float* b1 = (const float*)d_in[4];
    const float* W2 = (const float*)d_in[5];
    const float* b2 = (const float*)d_in[6];
    const float* W3 = (const float*)d_in[7];
    const float* b3 = (const float*)d_in[8];
    const float* W4 = (const float*)d_in[9];
    const float* b4 = (const float*)d_in[10];
    float* out = (float*)d_out;

    char* ws = (char*)d_ws;
    float*          dinv    = (float*)(ws + 0);                  // 40,960
    int*            cnt     = (int*)  (ws + 40960);              // 40,960
    int*            bucket  = (int*)  (ws + 81920);              // 5,120,000
    float*          Y4      = (float*)(ws + 5201920);            // 81,920
    unsigned short* xb      = (unsigned short*)(ws + 5283840);   // 45,875,200
    unsigned short* W1t     = (unsigned short*)(ws + 51159040);  // 2,293,760
    unsigned short* W2t     = (unsigned short*)(ws + 53452800);  // 524,288
    unsigned short* W3t     = (unsigned short*)(ws + 53977088);  // 524,288
    unsigned short* Yb      = (unsigned short*)(ws + 54501376);  // 10,485,760
    unsigned short* Hb      = (unsigned short*)(ws + 64987136);  // 10,485,760
    if (ws_size < 75472896) return;

    const int agrid = (MPAD * 64) / 256;  // one wave per (padded) node

    // d1: weight transposes + cnt zero
    k_prep<<<dim3(14, HDIM), 256, 0, stream>>>(W1, W2, W3, W1t, W2t, W3t, cnt);
    // d2: x->bf16 convert + bucketed hist/fill
    k_cvt_fill<<<MPAD + 625, 256, 0, stream>>>(x, xb, ei, cnt, bucket);
    // d3: layer-1 GEMM (x3 TELEMETRY) + dinv
    k_gemm1_dinv<<<GG1 + 40, 256, 0, stream>>>(xb, W1t, Yb, NNODES, K1PAD, cnt, dinv, 3);
    // d4: layer-1 aggregation (x4 TELEMETRY -> surfaces in rocprof top-5)
    k_agg<<<agrid, 256, 0, stream>>>(Yb, dinv, cnt, bucket, b1, Hb, 4);
    // d5/d6: layer 2 (normal)
    k_gemm_bf16<<<GG1, 256, 0, stream>>>(Hb, W2t, Yb, NNODES, HDIM);
    k_agg<<<agrid, 256, 0, stream>>>(Yb, dinv, cnt, bucket, b2, Hb, 1);
    // d7/d8: layer 3 + fused layer-4 GEMM
    k_gemm_bf16<<<GG1, 256, 0, stream>>>(Hb, W3t, Yb, NNODES, HDIM);
    k_agg_g4<<<(NNODES * 64) / 256, 256, 0, stream>>>(Yb, dinv, cnt, bucket, b3, W4, Y4);
    // d9: layer-4 aggregation + log_softmax
    k_final<<<40, 256, 0, stream>>>(Y4, dinv, cnt, bucket, b4, out, NNODES);
}

// Round 6
// 323.754 us; speedup vs baseline: 2.6959x; 1.2991x over previous
//
#include <hip/hip_runtime.h>
#include <hip/hip_bf16.h>

// Problem constants (fixed by the reference).
#define NNODES 10000
#define NEDGES 160000
#define FIN    2208
#define HDIM   512
#define NCLS   2

#define MPAD   10240     // 80 * 128
#define K1PAD  2240      // 2208 padded to multiple of 64
#define BCAP   128       // per-node edge bucket capacity (max degree ~35 here)

typedef __bf16 bf16x8 __attribute__((ext_vector_type(8)));
typedef float  f32x4  __attribute__((ext_vector_type(4)));
typedef unsigned short u16x8 __attribute__((ext_vector_type(8)));

__device__ inline unsigned short f2bf(float f) {
    union { float f; unsigned int u; } v; v.f = f;
    return (unsigned short)((v.u + 0x7FFFu + ((v.u >> 16) & 1u)) >> 16);
}
__device__ inline float bf2f(unsigned short u) {
    union { unsigned int i; float f; } v; v.i = ((unsigned int)u) << 16; return v.f;
}

// ---------------- dispatch 0: cnt zero (fill atomics need it) ----------------
__global__ void k_zero(int* __restrict__ cnt) {
    int i = blockIdx.x * 256 + threadIdx.x;
    if (i < NNODES) cnt[i] = 0;
}

// ---- dispatch 1: weight transposes + x->bf16 convert + edge fill (merged) ----
// blocks [0,7168): prep (bx%14 selects W1t/W2t/W3t slice, bx/14 = out col)
// blocks [7168, 17408): x->bf16 convert, one row per block
// blocks [17408, 18033): edge hist/fill into fixed-stride buckets
#define PREPB 7168
#define CVTB  10240
__global__ void k_prep_cvt_fill(
    const float* __restrict__ W1, const float* __restrict__ W2,
    const float* __restrict__ W3, unsigned short* __restrict__ W1t,
    unsigned short* __restrict__ W2t, unsigned short* __restrict__ W3t,
    const float* __restrict__ x, unsigned short* __restrict__ xb,
    const int* __restrict__ ei, int* __restrict__ cnt, int* __restrict__ bucket) {
    int b = blockIdx.x;
    int t = threadIdx.x;
    if (b < PREPB) {
        int bx = b % 14;
        int n  = b / 14;
        if (bx < 9) {
            int k = bx * 256 + t;
            if (k < K1PAD) {
                float v = (k < FIN) ? W1[(size_t)k * HDIM + n] : 0.0f;
                W1t[(size_t)n * K1PAD + k] = f2bf(v);
            }
        } else if (bx < 11) {
            int k = (bx - 9) * 256 + t;
            W2t[(size_t)n * HDIM + k] = f2bf(W2[(size_t)k * HDIM + n]);
        } else if (bx < 13) {
            int k = (bx - 11) * 256 + t;
            W3t[(size_t)n * HDIM + k] = f2bf(W3[(size_t)k * HDIM + n]);
        }
        // bx==13 slot: idle (cnt zero moved to k_zero)
        return;
    }
    if (b < PREPB + CVTB) {
        int row = b - PREPB;
        unsigned short* orow = xb + (size_t)row * K1PAD;
        u16x8 z = {0, 0, 0, 0, 0, 0, 0, 0};
        if (row >= NNODES) {
            for (int c = t; c < K1PAD / 8; c += 256) *(u16x8*)(orow + c * 8) = z;
            return;
        }
        const float* irow = x + (size_t)row * FIN;
        for (int c = t; c < K1PAD / 8; c += 256) {
            int col = c * 8;
            u16x8 o = z;
            if (col + 8 <= FIN) {
                float4 f0 = *(const float4*)(irow + col);
                float4 f1 = *(const float4*)(irow + col + 4);
                o[0] = f2bf(f0.x); o[1] = f2bf(f0.y); o[2] = f2bf(f0.z); o[3] = f2bf(f0.w);
                o[4] = f2bf(f1.x); o[5] = f2bf(f1.y); o[6] = f2bf(f1.z); o[7] = f2bf(f1.w);
            }
            *(u16x8*)(orow + col) = o;
        }
        return;
    }
    int i = (b - PREPB - CVTB) * 256 + t;
    if (i < NEDGES) {
        int src = ei[i];
        int dst = ei[NEDGES + i];
        int pos = atomicAdd(&cnt[dst], 1);
        bucket[dst * BCAP + pos] = src;
    }
}

// ---------------- bf16 MFMA GEMM body: 128x128 tile (m97 structure) ----------
// 32 MFMA per k-step per wave (vs 16 at 128x64) -> better barrier amortization;
// halves grid-wide A staging traffic. 32 KB LDS, acc 4x4, 4 waves (2x2).
#define BKK 64
#define GB1 320          // (10240/128) * (512/128)

__device__ __forceinline__ void gemm_body(
    const unsigned short* __restrict__ A, const unsigned short* __restrict__ Bt,
    unsigned short* __restrict__ C, int M, int K, int l) {
    __shared__ char As[128 * BKK * 2] __attribute__((aligned(16)));
    __shared__ char Bs[128 * BKK * 2] __attribute__((aligned(16)));
    const int tid  = threadIdx.x;
    const int lane = tid & 63;
    const int w    = tid >> 6;
    const int wm   = w & 1, wn = w >> 1;       // 2x2 wave grid
    const int quad = lane >> 4, lq = lane & 15;

    // XCD-aware swizzle over 320 blocks: l = xcd + 8*(bn4 + 4*s8)
    const int xcd   = l & 7;
    const int q     = l >> 3;                  // 0..39
    const int bn    = (q & 3) * 128;           // 4 col-blocks
    const int strip = (q >> 2) * 8 + xcd;      // 0..79
    const int bm    = strip * 128;

    f32x4 acc[4][4] = {};

    for (int k0 = 0; k0 < K; k0 += BKK) {
        #pragma unroll
        for (int i = 0; i < 4; ++i) {
            int c = i * 256 + tid;
            int r = c >> 3;
            int g = (c & 7) ^ (r & 7);
            const char* gpA = (const char*)A + ((size_t)(bm + r) * K + k0) * 2 + (g << 4);
            __builtin_amdgcn_global_load_lds(
                (const __attribute__((address_space(1))) void*)gpA,
                (__attribute__((address_space(3))) void*)(As + c * 16), 16, 0, 0);
        }
        #pragma unroll
        for (int i = 0; i < 4; ++i) {
            int c = i * 256 + tid;
            int r = c >> 3;
            int g = (c & 7) ^ (r & 7);
            const char* gpB = (const char*)Bt + ((size_t)(bn + r) * K + k0) * 2 + (g << 4);
            __builtin_amdgcn_global_load_lds(
                (const __attribute__((address_space(1))) void*)gpB,
                (__attribute__((address_space(3))) void*)(Bs + c * 16), 16, 0, 0);
        }
        __syncthreads();

        #pragma unroll
        for (int s = 0; s < 2; ++s) {
            bf16x8 af[4], bfr[4];
            int g = s * 4 + quad;
            #pragma unroll
            for (int i = 0; i < 4; ++i) {
                int r = wm * 64 + i * 16 + lq;
                af[i] = *(const bf16x8*)(As + r * 128 + ((g ^ (r & 7)) << 4));
            }
            #pragma unroll
            for (int j = 0; j < 4; ++j) {
                int n = wn * 64 + j * 16 + lq;
                bfr[j] = *(const bf16x8*)(Bs + n * 128 + ((g ^ (n & 7)) << 4));
            }
            #pragma unroll
            for (int i = 0; i < 4; ++i)
                #pragma unroll
                for (int j = 0; j < 4; ++j)
                    acc[i][j] = __builtin_amdgcn_mfma_f32_16x16x32_bf16(
                        af[i], bfr[j], acc[i][j], 0, 0, 0);
        }
        __syncthreads();
    }

    #pragma unroll
    for (int i = 0; i < 4; ++i) {
        #pragma unroll
        for (int p = 0; p < 4; ++p) {
            int r = bm + wm * 64 + i * 16 + quad * 4 + p;
            if (r < M) {
                #pragma unroll
                for (int j = 0; j < 4; ++j) {
                    int col = bn + wn * 64 + j * 16 + lq;
                    C[(size_t)r * HDIM + col] = f2bf(acc[i][j][p]);
                }
            }
        }
    }
}

// ---------------- dispatch 2: GEMM1 (320 blocks) + dinv compute (40) ----------
__global__ __launch_bounds__(256) void k_gemm1_dinv(
    const unsigned short* __restrict__ A, const unsigned short* __restrict__ Bt,
    unsigned short* __restrict__ C, int M, int K,
    const int* __restrict__ cnt, float* __restrict__ dinv) {
    int bx = blockIdx.x;
    if (bx < GB1) { gemm_body(A, Bt, C, M, K, bx); return; }
    int i = (bx - GB1) * 256 + threadIdx.x;
    if (i < NNODES) dinv[i] = rsqrtf((float)cnt[i] + 1.0f);
}

// ---------------- GEMM (layers 2/3) ----------------
__global__ __launch_bounds__(256) void k_gemm_bf16(
    const unsigned short* __restrict__ A, const unsigned short* __restrict__ Bt,
    unsigned short* __restrict__ C, int M, int K) {
    gemm_body(A, Bt, C, M, K, blockIdx.x);
}

// ---------------- aggregation (layers 1/2): 1 wave per node ----------------
// Measured 13.1 us (R4 telemetry) ~= L3 gather floor. Do not touch.
__global__ void k_agg(const unsigned short* __restrict__ Y, const float* __restrict__ dinv,
                      const int* __restrict__ cnt, const int* __restrict__ bucket,
                      const float* __restrict__ bias, unsigned short* __restrict__ Hb) {
    int w = (blockIdx.x * blockDim.x + threadIdx.x) >> 6;
    int lane = threadIdx.x & 63;
    if (w >= MPAD) return;
    unsigned short* hr = Hb + (size_t)w * HDIM + lane * 8;
    if (w >= NNODES) {
        u16x8 z = {0, 0, 0, 0, 0, 0, 0, 0};
        *(u16x8*)hr = z;
        return;
    }
    float di = dinv[w];
    float sw = di * di;
    u16x8 own = *(const u16x8*)(Y + (size_t)w * HDIM + lane * 8);
    float acc[8];
    #pragma unroll
    for (int t = 0; t < 8; ++t) acc[t] = sw * bf2f(own[t]);

    const int* col = bucket + w * BCAP;
    int deg = cnt[w];
    int e = 0;
    for (; e + 4 <= deg; e += 4) {
        int s0 = col[e + 0], s1 = col[e + 1];
        int s2 = col[e + 2], s3 = col[e + 3];
        float w0 = di * dinv[s0], w1 = di * dinv[s1];
        float w2 = di * dinv[s2], w3 = di * dinv[s3];
        u16x8 v0 = *(const u16x8*)(Y + (size_t)s0 * HDIM + lane * 8);
        u16x8 v1 = *(const u16x8*)(Y + (size_t)s1 * HDIM + lane * 8);
        u16x8 v2 = *(const u16x8*)(Y + (size_t)s2 * HDIM + lane * 8);
        u16x8 v3 = *(const u16x8*)(Y + (size_t)s3 * HDIM + lane * 8);
        #pragma unroll
        for (int t = 0; t < 8; ++t) {
            acc[t] += w0 * bf2f(v0[t]);
            acc[t] += w1 * bf2f(v1[t]);
            acc[t] += w2 * bf2f(v2[t]);
            acc[t] += w3 * bf2f(v3[t]);
        }
    }
    for (; e < deg; ++e) {
        int s = col[e];
        float wg = di * dinv[s];
        u16x8 v = *(const u16x8*)(Y + (size_t)s * HDIM + lane * 8);
        #pragma unroll
        for (int t = 0; t < 8; ++t) acc[t] += wg * bf2f(v[t]);
    }

    float4 b0 = ((const float4*)bias)[lane * 2];
    float4 b1 = ((const float4*)bias)[lane * 2 + 1];
    acc[0] += b0.x; acc[1] += b0.y; acc[2] += b0.z; acc[3] += b0.w;
    acc[4] += b1.x; acc[5] += b1.y; acc[6] += b1.z; acc[7] += b1.w;
    u16x8 o;
    #pragma unroll
    for (int t = 0; t < 8; ++t) o[t] = f2bf(fmaxf(acc[t], 0.0f));
    *(u16x8*)hr = o;
}

// ---------------- agg3 + relu + layer-4 GEMM fused ----------------
__global__ void k_agg_g4(const unsigned short* __restrict__ Y, const float* __restrict__ dinv,
                         const int* __restrict__ cnt, const int* __restrict__ bucket,
                         const float* __restrict__ b3, const float* __restrict__ W4,
                         float* __restrict__ Y4) {
    int w = (blockIdx.x * blockDim.x + threadIdx.x) >> 6;
    int lane = threadIdx.x & 63;
    if (w >= NNODES) return;
    float di = dinv[w];
    float sw = di * di;
    u16x8 own = *(const u16x8*)(Y + (size_t)w * HDIM + lane * 8);
    float acc[8];
    #pragma unroll
    for (int t = 0; t < 8; ++t) acc[t] = sw * bf2f(own[t]);

    const int* col = bucket + w * BCAP;
    int deg = cnt[w];
    int e = 0;
    for (; e + 4 <= deg; e += 4) {
        int s0 = col[e + 0], s1 = col[e + 1];
        int s2 = col[e + 2], s3 = col[e + 3];
        float w0 = di * dinv[s0], w1 = di * dinv[s1];
        float w2 = di * dinv[s2], w3 = di * dinv[s3];
        u16x8 v0 = *(const u16x8*)(Y + (size_t)s0 * HDIM + lane * 8);
        u16x8 v1 = *(const u16x8*)(Y + (size_t)s1 * HDIM + lane * 8);
        u16x8 v2 = *(const u16x8*)(Y + (size_t)s2 * HDIM + lane * 8);
        u16x8 v3 = *(const u16x8*)(Y + (size_t)s3 * HDIM + lane * 8);
        #pragma unroll
        for (int t = 0; t < 8; ++t) {
            acc[t] += w0 * bf2f(v0[t]);
            acc[t] += w1 * bf2f(v1[t]);
            acc[t] += w2 * bf2f(v2[t]);
            acc[t] += w3 * bf2f(v3[t]);
        }
    }
    for (; e < deg; ++e) {
        int s = col[e];
        float wg = di * dinv[s];
        u16x8 v = *(const u16x8*)(Y + (size_t)s * HDIM + lane * 8);
        #pragma unroll
        for (int t = 0; t < 8; ++t) acc[t] += wg * bf2f(v[t]);
    }

    float4 b0 = ((const float4*)b3)[lane * 2];
    float4 b1 = ((const float4*)b3)[lane * 2 + 1];
    acc[0] += b0.x; acc[1] += b0.y; acc[2] += b0.z; acc[3] += b0.w;
    acc[4] += b1.x; acc[5] += b1.y; acc[6] += b1.z; acc[7] += b1.w;
    #pragma unroll
    for (int t = 0; t < 8; ++t) acc[t] = fmaxf(acc[t], 0.0f);

    const float4* wf = (const float4*)W4;
    float4 w0 = wf[lane * 4 + 0];
    float4 w1 = wf[lane * 4 + 1];
    float4 w2 = wf[lane * 4 + 2];
    float4 w3 = wf[lane * 4 + 3];
    float z0 = acc[0]*w0.x + acc[1]*w0.z + acc[2]*w1.x + acc[3]*w1.z
             + acc[4]*w2.x + acc[5]*w2.z + acc[6]*w3.x + acc[7]*w3.z;
    float z1 = acc[0]*w0.y + acc[1]*w0.w + acc[2]*w1.y + acc[3]*w1.w
             + acc[4]*w2.y + acc[5]*w2.w + acc[6]*w3.y + acc[7]*w3.w;
    #pragma unroll
    for (int off = 32; off > 0; off >>= 1) {
        z0 += __shfl_down(z0, off);
        z1 += __shfl_down(z1, off);
    }
    if (lane == 0) {
        Y4[2 * w] = z0;
        Y4[2 * w + 1] = z1;
    }
}

// ---------------- layer-4 aggregation + bias + log_softmax ----------------
__global__ void k_final(const float* __restrict__ Y4, const float* __restrict__ dinv,
                        const int* __restrict__ cnt, const int* __restrict__ bucket,
                        const float* __restrict__ b4, float* __restrict__ out, int n) {
    int i = blockIdx.x * blockDim.x + threadIdx.x;
    if (i >= n) return;
    float di = dinv[i];
    float sw = di * di;
    float z0 = sw * Y4[2 * i];
    float z1 = sw * Y4[2 * i + 1];
    const int* col = bucket + i * BCAP;
    int deg = cnt[i];
    for (int e = 0; e < deg; ++e) {
        int s = col[e];
        float wgt = di * dinv[s];
        z0 += wgt * Y4[2 * s];
        z1 += wgt * Y4[2 * s + 1];
    }
    z0 += b4[0];
    z1 += b4[1];
    float m = fmaxf(z0, z1);
    float l = m + logf(expf(z0 - m) + expf(z1 - m));
    out[2 * i] = z0 - l;
    out[2 * i + 1] = z1 - l;
}

// ---------------- launch ----------------

extern "C" void kernel_launch(void* const* d_in, const int* in_sizes, int n_in,
                              void* d_out, int out_size, void* d_ws, size_t ws_size,
                              hipStream_t stream) {
    const float* x  = (const float*)d_in[0];
    const int*   ei = (const int*)d_in[1];
    const float* W1 = (const float*)d_in[3];
    const float* b1 = (const float*)d_in[4];
    const float* W2 = (const float*)d_in[5];
    const float* b2 = (const float*)d_in[6];
    const float* W3 = (const float*)d_in[7];
    const float* b3 = (const float*)d_in[8];
    const float* W4 = (const float*)d_in[9];
    const float* b4 = (const float*)d_in[10];
    float* out = (float*)d_out;

    char* ws = (char*)d_ws;
    float*          dinv    = (float*)(ws + 0);                  // 40,960
    int*            cnt     = (int*)  (ws + 40960);              // 40,960
    int*            bucket  = (int*)  (ws + 81920);              // 5,120,000
    float*          Y4      = (float*)(ws + 5201920);            // 81,920
    unsigned short* xb      = (unsigned short*)(ws + 5283840);   // 45,875,200
    unsigned short* W1t     = (unsigned short*)(ws + 51159040);  // 2,293,760
    unsigned short* W2t     = (unsigned short*)(ws + 53452800);  // 524,288
    unsigned short* W3t     = (unsigned short*)(ws + 53977088);  // 524,288
    unsigned short* Yb      = (unsigned short*)(ws + 54501376);  // 10,485,760
    unsigned short* Hb      = (unsigned short*)(ws + 64987136);  // 10,485,760
    if (ws_size < 75472896) return;

    const int agrid = (MPAD * 64) / 256;  // one wave per (padded) node

    // d0: cnt zero (tiny; fill atomics in d1 need it)
    k_zero<<<40, 256, 0, stream>>>(cnt);
    // d1: weight transposes + x->bf16 convert + edge fill (merged, independent parts)
    k_prep_cvt_fill<<<PREPB + CVTB + 625, 256, 0, stream>>>(
        W1, W2, W3, W1t, W2t, W3t, x, xb, ei, cnt, bucket);
    // d2: layer-1 GEMM (128x128 tiles, 320 blocks) + dinv compute
    k_gemm1_dinv<<<GB1 + 40, 256, 0, stream>>>(xb, W1t, Yb, NNODES, K1PAD, cnt, dinv);
    // d3: layer-1 aggregation
    k_agg<<<agrid, 256, 0, stream>>>(Yb, dinv, cnt, bucket, b1, Hb);
    // d4/d5: layer 2
    k_gemm_bf16<<<GB1, 256, 0, stream>>>(Hb, W2t, Yb, NNODES, HDIM);
    k_agg<<<agrid, 256, 0, stream>>>(Yb, dinv, cnt, bucket, b2, Hb);
    // d6/d7: layer 3 + fused layer-4 GEMM
    k_gemm_bf16<<<GB1, 256, 0, stream>>>(Hb, W3t, Yb, NNODES, HDIM);
    k_agg_g4<<<(NNODES * 64) / 256, 256, 0, stream>>>(Yb, dinv, cnt, bucket, b3, W4, Y4);
    // d8: layer-4 aggregation + log_softmax
    k_final<<<40, 256, 0, stream>>>(Y4, dinv, cnt, bucket, b4, out, NNODES);
}

// Round 7
// 302.106 us; speedup vs baseline: 2.8891x; 1.0717x over previous
//
#include <hip/hip_runtime.h>
#include <hip/hip_bf16.h>

// Problem constants (fixed by the reference).
#define NNODES 10000
#define NEDGES 160000
#define FIN    2208
#define HDIM   512
#define NCLS   2

#define MPAD   10240     // 80 * 128
#define K1PAD  2240      // 2208 padded to multiple of 64
#define BCAP   128       // per-node edge bucket capacity (max degree ~35 here)

typedef __bf16 bf16x8 __attribute__((ext_vector_type(8)));
typedef float  f32x4  __attribute__((ext_vector_type(4)));
typedef unsigned short u16x8 __attribute__((ext_vector_type(8)));

__device__ inline unsigned short f2bf(float f) {
    union { float f; unsigned int u; } v; v.f = f;
    return (unsigned short)((v.u + 0x7FFFu + ((v.u >> 16) & 1u)) >> 16);
}
__device__ inline float bf2f(unsigned short u) {
    union { unsigned int i; float f; } v; v.i = ((unsigned int)u) << 16; return v.f;
}

// ---------------- dispatch 0: cnt zero (fill atomics need it) ----------------
__global__ void k_zero(int* __restrict__ cnt) {
    int i = blockIdx.x * 256 + threadIdx.x;
    if (i < NNODES) cnt[i] = 0;
}

// ---- dispatch 1: LDS-tiled W transposes + x->bf16 convert + edge fill -------
// R6 postmortem: per-lane stride-2KB transpose reads were latency-bound (52us,
// 2.2 TB/s, VALUBusy 6%). Fix: classic 64x64 LDS tile transpose — coalesced
// 256B reads, conflict-free [64][65] LDS, coalesced 128B bf16 writes.
// blocks [0,280): W1 tiles (35 k-tiles x 8 n-tiles)
// blocks [280,344): W2 tiles (8x8), [344,408): W3 tiles
// blocks [408, 408+10240): x->bf16 convert, one row per block
// blocks [408+10240, +625): edge hist/fill
#define TRB   408
#define CVTB  10240
__global__ void k_prep_cvt_fill(
    const float* __restrict__ W1, const float* __restrict__ W2,
    const float* __restrict__ W3, unsigned short* __restrict__ W1t,
    unsigned short* __restrict__ W2t, unsigned short* __restrict__ W3t,
    const float* __restrict__ x, unsigned short* __restrict__ xb,
    const int* __restrict__ ei, int* __restrict__ cnt, int* __restrict__ bucket) {
    __shared__ float tl[64][65];
    int b = blockIdx.x;
    int t = threadIdx.x;
    if (b < TRB) {
        const float* Wsrc; unsigned short* Wdst; int kt, nt, Kdim, KP;
        if (b < 280)      { Wsrc = W1; Wdst = W1t; kt = b % 35;        nt = b / 35;        Kdim = FIN;  KP = K1PAD; }
        else if (b < 344) { Wsrc = W2; Wdst = W2t; kt = (b-280) % 8;   nt = (b-280) / 8;   Kdim = HDIM; KP = HDIM;  }
        else              { Wsrc = W3; Wdst = W3t; kt = (b-344) % 8;   nt = (b-344) / 8;   Kdim = HDIM; KP = HDIM;  }
        int wv = t >> 6, ln = t & 63;
        #pragma unroll
        for (int p = 0; p < 16; ++p) {
            int kl = p * 4 + wv;
            int k  = kt * 64 + kl;
            tl[kl][ln] = (k < Kdim) ? Wsrc[(size_t)k * HDIM + nt * 64 + ln] : 0.0f;
        }
        __syncthreads();
        #pragma unroll
        for (int p = 0; p < 16; ++p) {
            int nl = p * 4 + wv;
            Wdst[(size_t)(nt * 64 + nl) * KP + kt * 64 + ln] = f2bf(tl[ln][nl]);
        }
        return;
    }
    if (b < TRB + CVTB) {
        int row = b - TRB;
        unsigned short* orow = xb + (size_t)row * K1PAD;
        u16x8 z = {0, 0, 0, 0, 0, 0, 0, 0};
        if (row >= NNODES) {
            for (int c = t; c < K1PAD / 8; c += 256) *(u16x8*)(orow + c * 8) = z;
            return;
        }
        const float* irow = x + (size_t)row * FIN;
        for (int c = t; c < K1PAD / 8; c += 256) {
            int col = c * 8;
            u16x8 o = z;
            if (col + 8 <= FIN) {
                float4 f0 = *(const float4*)(irow + col);
                float4 f1 = *(const float4*)(irow + col + 4);
                o[0] = f2bf(f0.x); o[1] = f2bf(f0.y); o[2] = f2bf(f0.z); o[3] = f2bf(f0.w);
                o[4] = f2bf(f1.x); o[5] = f2bf(f1.y); o[6] = f2bf(f1.z); o[7] = f2bf(f1.w);
            }
            *(u16x8*)(orow + col) = o;
        }
        return;
    }
    int i = (b - TRB - CVTB) * 256 + t;
    if (i < NEDGES) {
        int src = ei[i];
        int dst = ei[NEDGES + i];
        int pos = atomicAdd(&cnt[dst], 1);
        bucket[dst * BCAP + pos] = src;
    }
}

// ---------------- bf16 MFMA GEMM body: verified 128x64 tile ----------------
// R6 postmortem: 128x128 (320 blocks, 1.25/CU) regressed — too few co-resident
// waves to hide the staging drain. 128x64 = 640 blocks (2.5/CU), measured
// gemm1 = 35.3 us (R4 telemetry). Reverted verbatim.
#define BKK 64
#define GG1 640

__device__ __forceinline__ void gemm_body(
    const unsigned short* __restrict__ A, const unsigned short* __restrict__ Bt,
    unsigned short* __restrict__ C, int M, int K, int l) {
    __shared__ char As[128 * BKK * 2] __attribute__((aligned(16)));
    __shared__ char Bs[64 * BKK * 2]  __attribute__((aligned(16)));
    const int tid  = threadIdx.x;
    const int lane = tid & 63;
    const int w    = tid >> 6;
    const int wm   = w & 1, wn = w >> 1;
    const int quad = lane >> 4, lq = lane & 15;

    const int xcd   = l & 7;
    const int q     = l >> 3;
    const int strip = (q >> 3) * 8 + xcd;
    const int bm    = strip * 128;
    const int bn    = (q & 7) * 64;

    f32x4 acc[4][2] = {};

    for (int k0 = 0; k0 < K; k0 += BKK) {
        #pragma unroll
        for (int i = 0; i < 4; ++i) {
            int c = i * 256 + tid;
            int r = c >> 3;
            int g = (c & 7) ^ (r & 7);
            const char* gpA = (const char*)A + ((size_t)(bm + r) * K + k0) * 2 + (g << 4);
            __builtin_amdgcn_global_load_lds(
                (const __attribute__((address_space(1))) void*)gpA,
                (__attribute__((address_space(3))) void*)(As + c * 16), 16, 0, 0);
        }
        #pragma unroll
        for (int i = 0; i < 2; ++i) {
            int c = i * 256 + tid;
            int r = c >> 3;
            int g = (c & 7) ^ (r & 7);
            const char* gpB = (const char*)Bt + ((size_t)(bn + r) * K + k0) * 2 + (g << 4);
            __builtin_amdgcn_global_load_lds(
                (const __attribute__((address_space(1))) void*)gpB,
                (__attribute__((address_space(3))) void*)(Bs + c * 16), 16, 0, 0);
        }
        __syncthreads();

        #pragma unroll
        for (int s = 0; s < 2; ++s) {
            bf16x8 af[4], bfr[2];
            int g = s * 4 + quad;
            #pragma unroll
            for (int i = 0; i < 4; ++i) {
                int r = wm * 64 + i * 16 + lq;
                af[i] = *(const bf16x8*)(As + r * 128 + ((g ^ (r & 7)) << 4));
            }
            #pragma unroll
            for (int j = 0; j < 2; ++j) {
                int n = wn * 32 + j * 16 + lq;
                bfr[j] = *(const bf16x8*)(Bs + n * 128 + ((g ^ (n & 7)) << 4));
            }
            #pragma unroll
            for (int i = 0; i < 4; ++i)
                #pragma unroll
                for (int j = 0; j < 2; ++j)
                    acc[i][j] = __builtin_amdgcn_mfma_f32_16x16x32_bf16(
                        af[i], bfr[j], acc[i][j], 0, 0, 0);
        }
        __syncthreads();
    }

    #pragma unroll
    for (int i = 0; i < 4; ++i) {
        #pragma unroll
        for (int p = 0; p < 4; ++p) {
            int r = bm + wm * 64 + i * 16 + quad * 4 + p;
            if (r < M) {
                #pragma unroll
                for (int j = 0; j < 2; ++j) {
                    int col = bn + wn * 32 + j * 16 + lq;
                    C[(size_t)r * HDIM + col] = f2bf(acc[i][j][p]);
                }
            }
        }
    }
}

// ---------------- dispatch 2: GEMM1 (640 blocks) + dinv compute (40) ----------
__global__ __launch_bounds__(256) void k_gemm1_dinv(
    const unsigned short* __restrict__ A, const unsigned short* __restrict__ Bt,
    unsigned short* __restrict__ C, int M, int K,
    const int* __restrict__ cnt, float* __restrict__ dinv) {
    int bx = blockIdx.x;
    if (bx < GG1) { gemm_body(A, Bt, C, M, K, bx); return; }
    int i = (bx - GG1) * 256 + threadIdx.x;
    if (i < NNODES) dinv[i] = rsqrtf((float)cnt[i] + 1.0f);
}

// ---------------- GEMM (layers 2/3) ----------------
__global__ __launch_bounds__(256) void k_gemm_bf16(
    const unsigned short* __restrict__ A, const unsigned short* __restrict__ Bt,
    unsigned short* __restrict__ C, int M, int K) {
    gemm_body(A, Bt, C, M, K, blockIdx.x);
}

// ---------------- aggregation (layers 1/2): 1 wave per node ----------------
// Measured 13.1 us (R4 telemetry) ~= L3 gather floor. Do not touch.
__global__ void k_agg(const unsigned short* __restrict__ Y, const float* __restrict__ dinv,
                      const int* __restrict__ cnt, const int* __restrict__ bucket,
                      const float* __restrict__ bias, unsigned short* __restrict__ Hb) {
    int w = (blockIdx.x * blockDim.x + threadIdx.x) >> 6;
    int lane = threadIdx.x & 63;
    if (w >= MPAD) return;
    unsigned short* hr = Hb + (size_t)w * HDIM + lane * 8;
    if (w >= NNODES) {
        u16x8 z = {0, 0, 0, 0, 0, 0, 0, 0};
        *(u16x8*)hr = z;
        return;
    }
    float di = dinv[w];
    float sw = di * di;
    u16x8 own = *(const u16x8*)(Y + (size_t)w * HDIM + lane * 8);
    float acc[8];
    #pragma unroll
    for (int t = 0; t < 8; ++t) acc[t] = sw * bf2f(own[t]);

    const int* col = bucket + w * BCAP;
    int deg = cnt[w];
    int e = 0;
    for (; e + 4 <= deg; e += 4) {
        int s0 = col[e + 0], s1 = col[e + 1];
        int s2 = col[e + 2], s3 = col[e + 3];
        float w0 = di * dinv[s0], w1 = di * dinv[s1];
        float w2 = di * dinv[s2], w3 = di * dinv[s3];
        u16x8 v0 = *(const u16x8*)(Y + (size_t)s0 * HDIM + lane * 8);
        u16x8 v1 = *(const u16x8*)(Y + (size_t)s1 * HDIM + lane * 8);
        u16x8 v2 = *(const u16x8*)(Y + (size_t)s2 * HDIM + lane * 8);
        u16x8 v3 = *(const u16x8*)(Y + (size_t)s3 * HDIM + lane * 8);
        #pragma unroll
        for (int t = 0; t < 8; ++t) {
            acc[t] += w0 * bf2f(v0[t]);
            acc[t] += w1 * bf2f(v1[t]);
            acc[t] += w2 * bf2f(v2[t]);
            acc[t] += w3 * bf2f(v3[t]);
        }
    }
    for (; e < deg; ++e) {
        int s = col[e];
        float wg = di * dinv[s];
        u16x8 v = *(const u16x8*)(Y + (size_t)s * HDIM + lane * 8);
        #pragma unroll
        for (int t = 0; t < 8; ++t) acc[t] += wg * bf2f(v[t]);
    }

    float4 b0 = ((const float4*)bias)[lane * 2];
    float4 b1 = ((const float4*)bias)[lane * 2 + 1];
    acc[0] += b0.x; acc[1] += b0.y; acc[2] += b0.z; acc[3] += b0.w;
    acc[4] += b1.x; acc[5] += b1.y; acc[6] += b1.z; acc[7] += b1.w;
    u16x8 o;
    #pragma unroll
    for (int t = 0; t < 8; ++t) o[t] = f2bf(fmaxf(acc[t], 0.0f));
    *(u16x8*)hr = o;
}

// ---------------- agg3 + relu + layer-4 GEMM fused ----------------
__global__ void k_agg_g4(const unsigned short* __restrict__ Y, const float* __restrict__ dinv,
                         const int* __restrict__ cnt, const int* __restrict__ bucket,
                         const float* __restrict__ b3, const float* __restrict__ W4,
                         float* __restrict__ Y4) {
    int w = (blockIdx.x * blockDim.x + threadIdx.x) >> 6;
    int lane = threadIdx.x & 63;
    if (w >= NNODES) return;
    float di = dinv[w];
    float sw = di * di;
    u16x8 own = *(const u16x8*)(Y + (size_t)w * HDIM + lane * 8);
    float acc[8];
    #pragma unroll
    for (int t = 0; t < 8; ++t) acc[t] = sw * bf2f(own[t]);

    const int* col = bucket + w * BCAP;
    int deg = cnt[w];
    int e = 0;
    for (; e + 4 <= deg; e += 4) {
        int s0 = col[e + 0], s1 = col[e + 1];
        int s2 = col[e + 2], s3 = col[e + 3];
        float w0 = di * dinv[s0], w1 = di * dinv[s1];
        float w2 = di * dinv[s2], w3 = di * dinv[s3];
        u16x8 v0 = *(const u16x8*)(Y + (size_t)s0 * HDIM + lane * 8);
        u16x8 v1 = *(const u16x8*)(Y + (size_t)s1 * HDIM + lane * 8);
        u16x8 v2 = *(const u16x8*)(Y + (size_t)s2 * HDIM + lane * 8);
        u16x8 v3 = *(const u16x8*)(Y + (size_t)s3 * HDIM + lane * 8);
        #pragma unroll
        for (int t = 0; t < 8; ++t) {
            acc[t] += w0 * bf2f(v0[t]);
            acc[t] += w1 * bf2f(v1[t]);
            acc[t] += w2 * bf2f(v2[t]);
            acc[t] += w3 * bf2f(v3[t]);
        }
    }
    for (; e < deg; ++e) {
        int s = col[e];
        float wg = di * dinv[s];
        u16x8 v = *(const u16x8*)(Y + (size_t)s * HDIM + lane * 8);
        #pragma unroll
        for (int t = 0; t < 8; ++t) acc[t] += wg * bf2f(v[t]);
    }

    float4 b0 = ((const float4*)b3)[lane * 2];
    float4 b1 = ((const float4*)b3)[lane * 2 + 1];
    acc[0] += b0.x; acc[1] += b0.y; acc[2] += b0.z; acc[3] += b0.w;
    acc[4] += b1.x; acc[5] += b1.y; acc[6] += b1.z; acc[7] += b1.w;
    #pragma unroll
    for (int t = 0; t < 8; ++t) acc[t] = fmaxf(acc[t], 0.0f);

    const float4* wf = (const float4*)W4;
    float4 w0 = wf[lane * 4 + 0];
    float4 w1 = wf[lane * 4 + 1];
    float4 w2 = wf[lane * 4 + 2];
    float4 w3 = wf[lane * 4 + 3];
    float z0 = acc[0]*w0.x + acc[1]*w0.z + acc[2]*w1.x + acc[3]*w1.z
             + acc[4]*w2.x + acc[5]*w2.z + acc[6]*w3.x + acc[7]*w3.z;
    float z1 = acc[0]*w0.y + acc[1]*w0.w + acc[2]*w1.y + acc[3]*w1.w
             + acc[4]*w2.y + acc[5]*w2.w + acc[6]*w3.y + acc[7]*w3.w;
    #pragma unroll
    for (int off = 32; off > 0; off >>= 1) {
        z0 += __shfl_down(z0, off);
        z1 += __shfl_down(z1, off);
    }
    if (lane == 0) {
        Y4[2 * w] = z0;
        Y4[2 * w + 1] = z1;
    }
}

// ---------------- layer-4 aggregation + bias + log_softmax ----------------
__global__ void k_final(const float* __restrict__ Y4, const float* __restrict__ dinv,
                        const int* __restrict__ cnt, const int* __restrict__ bucket,
                        const float* __restrict__ b4, float* __restrict__ out, int n) {
    int i = blockIdx.x * blockDim.x + threadIdx.x;
    if (i >= n) return;
    float di = dinv[i];
    float sw = di * di;
    float z0 = sw * Y4[2 * i];
    float z1 = sw * Y4[2 * i + 1];
    const int* col = bucket + i * BCAP;
    int deg = cnt[i];
    for (int e = 0; e < deg; ++e) {
        int s = col[e];
        float wgt = di * dinv[s];
        z0 += wgt * Y4[2 * s];
        z1 += wgt * Y4[2 * s + 1];
    }
    z0 += b4[0];
    z1 += b4[1];
    float m = fmaxf(z0, z1);
    float l = m + logf(expf(z0 - m) + expf(z1 - m));
    out[2 * i] = z0 - l;
    out[2 * i + 1] = z1 - l;
}

// ---------------- launch ----------------

extern "C" void kernel_launch(void* const* d_in, const int* in_sizes, int n_in,
                              void* d_out, int out_size, void* d_ws, size_t ws_size,
                              hipStream_t stream) {
    const float* x  = (const float*)d_in[0];
    const int*   ei = (const int*)d_in[1];
    const float* W1 = (const float*)d_in[3];
    const float* b1 = (const float*)d_in[4];
    const float* W2 = (const float*)d_in[5];
    const float* b2 = (const float*)d_in[6];
    const float* W3 = (const float*)d_in[7];
    const float* b3 = (const float*)d_in[8];
    const float* W4 = (const float*)d_in[9];
    const float* b4 = (const float*)d_in[10];
    float* out = (float*)d_out;

    char* ws = (char*)d_ws;
    float*          dinv    = (float*)(ws + 0);                  // 40,960
    int*            cnt     = (int*)  (ws + 40960);              // 40,960
    int*            bucket  = (int*)  (ws + 81920);              // 5,120,000
    float*          Y4      = (float*)(ws + 5201920);            // 81,920
    unsigned short* xb      = (unsigned short*)(ws + 5283840);   // 45,875,200
    unsigned short* W1t     = (unsigned short*)(ws + 51159040);  // 2,293,760
    unsigned short* W2t     = (unsigned short*)(ws + 53452800);  // 524,288
    unsigned short* W3t     = (unsigned short*)(ws + 53977088);  // 524,288
    unsigned short* Yb      = (unsigned short*)(ws + 54501376);  // 10,485,760
    unsigned short* Hb      = (unsigned short*)(ws + 64987136);  // 10,485,760
    if (ws_size < 75472896) return;

    const int agrid = (MPAD * 64) / 256;  // one wave per (padded) node

    // d0: cnt zero (tiny; fill atomics in d1 need it)
    k_zero<<<40, 256, 0, stream>>>(cnt);
    // d1: tiled W transposes + x->bf16 convert + edge fill (merged)
    k_prep_cvt_fill<<<TRB + CVTB + 625, 256, 0, stream>>>(
        W1, W2, W3, W1t, W2t, W3t, x, xb, ei, cnt, bucket);
    // d2: layer-1 GEMM (128x64 tiles, 640 blocks) + dinv compute
    k_gemm1_dinv<<<GG1 + 40, 256, 0, stream>>>(xb, W1t, Yb, NNODES, K1PAD, cnt, dinv);
    // d3: layer-1 aggregation
    k_agg<<<agrid, 256, 0, stream>>>(Yb, dinv, cnt, bucket, b1, Hb);
    // d4/d5: layer 2
    k_gemm_bf16<<<GG1, 256, 0, stream>>>(Hb, W2t, Yb, NNODES, HDIM);
    k_agg<<<agrid, 256, 0, stream>>>(Yb, dinv, cnt, bucket, b2, Hb);
    // d6/d7: layer 3 + fused layer-4 GEMM
    k_gemm_bf16<<<GG1, 256, 0, stream>>>(Hb, W3t, Yb, NNODES, HDIM);
    k_agg_g4<<<(NNODES * 64) / 256, 256, 0, stream>>>(Yb, dinv, cnt, bucket, b3, W4, Y4);
    // d8: layer-4 aggregation + log_softmax
    k_final<<<40, 256, 0, stream>>>(Y4, dinv, cnt, bucket, b4, out, NNODES);
}